// Round 13
// baseline (452.994 us; speedup 1.0000x reference)
//
#include <hip/hip_runtime.h>

// MVGRL encoder, MI355X gfx950. Round 13: input-warming kernel (L3 prefetch) + fused ws zeroing.
#define NN 4096
#define NE 65536
#define NBAG 16
#define BFD 8192
#define CIN 128
#define HIDC 512
#define NG 64
#define ALPHA_C 0.2f
#define BETA_C 0.8f
#define K_CH 8
#define K_W 8

typedef unsigned short u16;
typedef __attribute__((ext_vector_type(8))) short short8;
typedef __attribute__((ext_vector_type(4))) short short4v;
typedef __attribute__((ext_vector_type(4))) float f32x4;
typedef __attribute__((ext_vector_type(2))) float f32x2;

__device__ __forceinline__ short f2bf(float f){
  unsigned u = __float_as_uint(f);
  u += 0x7fffu + ((u >> 16) & 1u);
  return (short)(u >> 16);
}
__device__ __forceinline__ float bf2f(u16 h){
  return __uint_as_float(((unsigned)h) << 16);
}
__device__ __forceinline__ void gload16(const void* g, const void* l){
  __builtin_amdgcn_global_load_lds(
    (const __attribute__((address_space(1))) unsigned int*)g,
    (__attribute__((address_space(3))) unsigned int*)l, 16, 0, 0);
}

// ---------- input warm (L3 prefetch) + workspace zeroing ----------
struct WarmPack { const float* p[16]; int n4[16]; };
__global__ __launch_bounds__(256) void k_warm(WarmPack wp, float* __restrict__ zero0, int zn4,
                                              float* __restrict__ sink){
  int gtid = blockIdx.x*256 + threadIdx.x, gsz = gridDim.x*256;
  f32x4 zv = {0,0,0,0};
  for (int i = gtid; i < zn4; i += gsz) ((f32x4*)zero0)[i] = zv;
  float acc = 0.f;
  #pragma unroll 1
  for (int s = 0; s < 16; ++s){
    const f32x4* p = (const f32x4*)wp.p[s];
    int n = wp.n4[s];
    for (int i = gtid; i < n; i += gsz){
      f32x4 v = p[i];
      acc += v[0] + v[1] + v[2] + v[3];
    }
  }
  sink[gtid & 4095] = acc;   // dead scratch; prevents DCE of warm reads
}

// ---------- merged prep: embed | edge scatter | batch hist ----------
__global__ void k_prep0(const float* __restrict__ cb, const int* __restrict__ xidx,
                        float* __restrict__ xf, u16* __restrict__ xfbf,
                        const int* __restrict__ ei, unsigned* __restrict__ Ab,
                        unsigned* __restrict__ ATb, int* __restrict__ cntD,
                        const int* __restrict__ batch, int* __restrict__ bcnt){
  int bx = blockIdx.x;
  if (bx < 2048){
    int n = bx*2 + (threadIdx.x >> 7);
    int c = threadIdx.x & 127;
    float acc = 0.f; int cnt = 0;
    #pragma unroll
    for (int b = 0; b < NBAG; ++b){
      int id = xidx[n*NBAG + b];
      if (id != BFD){ acc += cb[(size_t)id*CIN + c]; ++cnt; }
    }
    float v = acc / (float)(cnt > 0 ? cnt : 1);
    xf[(size_t)n*CIN + c] = v;
    xfbf[(size_t)n*CIN + c] = (u16)f2bf(v);
  } else if (bx < 2304){
    int e = (bx - 2048)*256 + threadIdx.x;
    int s = ei[e], d = ei[NE + e];
    atomicOr(&Ab[s*128 + (d >> 5)], 1u << (d & 31));
    atomicOr(&ATb[d*128 + (s >> 5)], 1u << (s & 31));
    atomicAdd(&cntD[d], 1);
  } else {
    int n = (bx - 2304)*256 + threadIdx.x;
    if (n < NN) atomicAdd(&bcnt[batch[n]], 1);
  }
}

// popcount rows; A-side writes di directly, AT-side writes cntAT
__global__ void k_popc2(const unsigned* __restrict__ Ab, const unsigned* __restrict__ ATb,
                        float* __restrict__ di, int* __restrict__ cntAT){
  int wid = (blockIdx.x*blockDim.x + threadIdx.x) >> 6;
  int lane = threadIdx.x & 63;
  if (wid >= 2*NN) return;
  const unsigned* bits; int r;
  if (wid < NN){ bits = Ab; r = wid; }
  else { bits = ATb; r = wid - NN; }
  int s = __popc(bits[r*128 + lane]) + __popc(bits[r*128 + 64 + lane]);
  #pragma unroll
  for (int off = 32; off > 0; off >>= 1) s += __shfl_down(s, off);
  if (lane == 0){
    if (wid < NN) di[r] = rsqrtf((float)s + 1.0f);
    else cntAT[r] = s;
  }
}

// three exclusive prefix sums; block 1 also emits dis = rsqrt(cntD+1)
__global__ void k_prefix3(const int* __restrict__ c0, int* __restrict__ r0, int n0,
                          const int* __restrict__ c1, int* __restrict__ r1, int n1,
                          const int* __restrict__ c2, int* __restrict__ r2, int n2,
                          float* __restrict__ dis){
  const int* cnt; int* rp; int n;
  if (blockIdx.x == 0){ cnt = c0; rp = r0; n = n0; }
  else if (blockIdx.x == 1){ cnt = c1; rp = r1; n = n1; }
  else { cnt = c2; rp = r2; n = n2; }
  __shared__ int a[4096];
  __shared__ int ps[1024];
  int t = threadIdx.x;
  for (int i = t; i < 4096; i += 1024) a[i] = (i < n) ? cnt[i] : 0;
  __syncthreads();
  if (blockIdx.x == 1){
    for (int i = t; i < NN; i += 1024) dis[i] = rsqrtf((float)a[i] + 1.0f);
  }
  int b0 = a[t*4], b1 = a[t*4+1], b2 = a[t*4+2], b3 = a[t*4+3];
  int s0 = b0, s1 = s0+b1, s2 = s1+b2, s3 = s2+b3;
  ps[t] = s3;
  __syncthreads();
  for (int off = 1; off < 1024; off <<= 1){
    int v = ps[t];
    int u = (t >= off) ? ps[t-off] : 0;
    __syncthreads();
    ps[t] = v + u;
    __syncthreads();
  }
  int excl = (t > 0) ? ps[t-1] : 0;
  int base = t*4;
  if (base     < n) rp[base]   = excl;
  if (base + 1 < n) rp[base+1] = excl + s0;
  if (base + 2 < n) rp[base+2] = excl + s1;
  if (base + 3 < n) rp[base+3] = excl + s2;
  if (t == 1023) rp[n] = ps[1023];
}

// ---------- weight descriptors ----------
struct WDesc { const float* src; u16* dst; int K; int N; };
struct WPack { WDesc w[12]; };

// CSR fill + weight convert in one launch
__global__ void k_fillwconv(const unsigned* __restrict__ bits, const int* __restrict__ rpA,
                            int* __restrict__ colidx,
                            const int* __restrict__ ei, const int* __restrict__ rpD,
                            int* __restrict__ cur, int* __restrict__ srcs,
                            WPack p){
  int bx = blockIdx.x;
  if (bx < 1024){
    int wid = (bx*blockDim.x + threadIdx.x) >> 6;
    int lane = threadIdx.x & 63;
    unsigned w0 = bits[wid*128 + lane];
    unsigned w1 = bits[wid*128 + 64 + lane];
    int c = __popc(w0) + __popc(w1);
    int x = c;
    #pragma unroll
    for (int d = 1; d < 64; d <<= 1){
      int y = __shfl_up(x, d);
      if (lane >= d) x += y;
    }
    int pos = rpA[wid] + (x - c);
    while (w0){ int b = __ffs(w0) - 1; w0 &= w0 - 1; colidx[pos++] = lane*32 + b; }
    while (w1){ int b = __ffs(w1) - 1; w1 &= w1 - 1; colidx[pos++] = (64 + lane)*32 + b; }
  } else if (bx < 1280){
    int e = (bx - 1024)*256 + threadIdx.x;
    int s = ei[e], d = ei[NE + e];
    int pos = atomicAdd(&cur[d], 1);
    srcs[rpD[d] + pos] = s;
  } else {
    int t5 = bx - 1280;
    int z = t5 >> 9;
    int rem = t5 & 511;
    int ky = rem >> 4, nx = rem & 15;
    WDesc d = p.w[z];
    int k0 = ky*32, n0 = nx*32;
    if (k0 >= d.K || n0 >= d.N) return;
    __shared__ float t[32][33];
    int tx = threadIdx.x & 31, ty = threadIdx.x >> 5;
    #pragma unroll
    for (int r = 0; r < 4; ++r){
      int row = ty + r*8;
      t[row][tx] = d.src[(size_t)(k0 + row)*d.N + n0 + tx];
    }
    __syncthreads();
    #pragma unroll
    for (int r = 0; r < 4; ++r){
      int row = ty + r*8;
      d.dst[(size_t)(n0 + row)*d.K + k0 + tx] = (u16)f2bf(t[tx][row]);
    }
  }
}

// ---------- sparse-tower GCN aggregation (wave per row, shuffle-broadcast, bf16 U) ----------
__global__ __launch_bounds__(256) void k_gcn_sp(const u16* __restrict__ U, float* __restrict__ out,
    u16* __restrict__ outbf,
    const int* __restrict__ rp, const int* __restrict__ srcs, const float* __restrict__ dis,
    const float* __restrict__ bias, const float* __restrict__ avec){
  int wid = (blockIdx.x*256 + threadIdx.x) >> 6;
  int lane = threadIdx.x & 63;
  if (wid >= NN) return;
  int j = wid;
  f32x4 a0 = {0,0,0,0}, a1 = {0,0,0,0};
  int b = rp[j], e = rp[j+1];
  for (int base = b; base < e; base += 64){
    int idx = base + lane;
    int myc = 0; float myd = 0.f;
    if (idx < e){ myc = srcs[idx]; myd = dis[myc]; }
    int m = min(64, e - base);
    for (int k = 0; k < m; ++k){
      int s = __shfl(myc, k); float w = __shfl(myd, k);
      const u16* Us = U + (size_t)s*HIDC;
      short4v q0 = *(const short4v*)(Us + lane*4);
      short4v q1 = *(const short4v*)(Us + 256 + lane*4);
      #pragma unroll
      for (int r = 0; r < 4; ++r){
        a0[r] += w*bf2f((u16)q0[r]);
        a1[r] += w*bf2f((u16)q1[r]);
      }
    }
  }
  float dj = dis[j];
  const u16* Uj = U + (size_t)j*HIDC;
  short4v s0 = *(const short4v*)(Uj + lane*4);
  short4v s1 = *(const short4v*)(Uj + 256 + lane*4);
  #pragma unroll
  for (int r = 0; r < 4; ++r){
    a0[r] += dj*bf2f((u16)s0[r]);
    a1[r] += dj*bf2f((u16)s1[r]);
  }
  float* op = out + (size_t)j*HIDC;
  u16* ob = outbf + (size_t)j*HIDC;
  #pragma unroll
  for (int v = 0; v < 4; ++v){
    int c0 = lane*4 + v, c1 = 256 + lane*4 + v;
    float x0 = dj*a0[v] + bias[c0]; float p0 = avec[c0];
    float r0 = x0 >= 0.f ? x0 : p0*x0;
    op[c0] = r0; ob[c0] = (u16)f2bf(r0);
    float x1 = dj*a1[v] + bias[c1]; float p1 = avec[c1];
    float r1 = x1 >= 0.f ? x1 : p1*x1;
    op[c1] = r1; ob[c1] = (u16)f2bf(r1);
  }
}

// ---------- Chebyshev w-step. MODE 0: first; 1: mid; 2: final -> dc + fused Z prep ----------
template<int MODE>
__global__ __launch_bounds__(256) void k_wstep(const float* __restrict__ w, const float* wp,
    float* __restrict__ wn, const int* __restrict__ rp, const int* __restrict__ cols,
    const float* __restrict__ di, float* __restrict__ dcv, float om,
    const float* __restrict__ xf, float* __restrict__ Zb128){
  int wid = (blockIdx.x*256 + threadIdx.x) >> 6;
  int lane = threadIdx.x & 63;
  if (wid >= NN) return;
  int b = rp[wid], e = rp[wid+1];
  float acc = 0.f;
  for (int k = b + lane; k < e; k += 64){
    int i = cols[k];
    float wi = (MODE == 0) ? ALPHA_C : w[i];
    acc += di[i]*wi;
  }
  #pragma unroll
  for (int o = 32; o > 0; o >>= 1) acc += __shfl_xor(acc, o);
  float dj = di[wid];
  float wj = (MODE == 0) ? ALPHA_C : w[wid];
  float basic = ALPHA_C + BETA_C*dj*(acc + dj*wj);
  float v = (MODE == 0) ? basic : (om*basic + (1.f - om)*wp[wid]);
  if (MODE == 2){
    float d2 = rsqrtf(fmaxf(v + 1.0f, 1e-12f));
    if (lane == 0) dcv[wid] = d2;
    f32x2 xv = *(const f32x2*)(xf + (size_t)wid*128 + lane*2);
    f32x2 z; z[0] = ALPHA_C*d2*xv[0]; z[1] = ALPHA_C*d2*xv[1];
    *(f32x2*)(Zb128 + (size_t)wid*128 + lane*2) = z;
  } else {
    if (lane == 0) wn[wid] = v;
  }
}

// ---------- Chebyshev step C=128, wave per row, shuffle-broadcast (f32) ----------
template<int FIN>
__global__ __launch_bounds__(256) void k_b128(const float* __restrict__ X, const float* __restrict__ Z,
    const float* Xp, float* Xn, u16* __restrict__ Pxbf,
    const int* __restrict__ rp, const int* __restrict__ cols,
    const float* __restrict__ di, float om,
    const float* __restrict__ dcv, const float* __restrict__ xf){
  int wid = (blockIdx.x*256 + threadIdx.x) >> 6;
  int lane = threadIdx.x & 63;
  if (wid >= NN) return;
  int j = wid;
  int b = rp[j], e = rp[j+1];
  float dj = di[j];
  f32x2 a0 = {0,0};
  for (int base = b; base < e; base += 64){
    int idx = base + lane;
    int myc = 0; float myd = 0.f;
    if (idx < e){ myc = cols[idx]; myd = di[myc]; }
    int m = min(64, e - base);
    for (int k = 0; k < m; ++k){
      int i = __shfl(myc, k); float w = __shfl(myd, k);
      a0 += w * (*(const f32x2*)(X + (size_t)i*128 + lane*2));
    }
  }
  a0 += dj * (*(const f32x2*)(X + (size_t)j*128 + lane*2));
  f32x2 basic = *(const f32x2*)(Z + (size_t)j*128 + lane*2) + (BETA_C*dj)*a0;
  f32x2 xp = *(const f32x2*)(Xp + (size_t)j*128 + lane*2);
  f32x2 v; v[0] = om*basic[0] + (1.f-om)*xp[0]; v[1] = om*basic[1] + (1.f-om)*xp[1];
  if constexpr (FIN){
    float d2 = dcv[j];
    f32x2 fv = *(const f32x2*)(xf + (size_t)j*128 + lane*2);
    unsigned pk = (unsigned)(unsigned short)f2bf(d2*(v[0] + d2*fv[0]))
                | ((unsigned)(unsigned short)f2bf(d2*(v[1] + d2*fv[1])) << 16);
    *(unsigned*)(Pxbf + (size_t)j*128 + lane*2) = pk;
  } else {
    *(f32x2*)(Xn + (size_t)j*128 + lane*2) = v;
  }
}

// ---------- Chebyshev step C=512, bf16 iterates, 1 wave/row dual-half ----------
template<int FIN>
__global__ __launch_bounds__(256) void k_b512h(const u16* __restrict__ X, const float* __restrict__ Z,
    const u16* Xp, u16* Xn, float* __restrict__ zo, u16* __restrict__ zobf,
    const int* __restrict__ rp, const int* __restrict__ cols,
    const float* __restrict__ di, float om,
    const float* __restrict__ dcv, const u16* __restrict__ Ubf,
    const float* __restrict__ bias, const float* __restrict__ avec){
  int wid = (blockIdx.x*256 + threadIdx.x) >> 6;
  int lane = threadIdx.x & 63;
  if (wid >= NN) return;
  int b = rp[wid], e = rp[wid+1];
  float dj = di[wid];
  const int co0 = lane*4, co1 = 256 + lane*4;
  f32x4 a0 = {0,0,0,0}, a1 = {0,0,0,0};
  for (int base = b; base < e; base += 64){
    int idx = base + lane;
    int myc = 0; float myd = 0.f;
    if (idx < e){ myc = cols[idx]; myd = di[myc]; }
    int m = min(64, e - base);
    for (int k = 0; k < m; ++k){
      int i = __shfl(myc, k); float w = __shfl(myd, k);
      const u16* Xi = X + (size_t)i*512;
      short4v x0 = *(const short4v*)(Xi + co0);
      short4v x1 = *(const short4v*)(Xi + co1);
      #pragma unroll
      for (int q = 0; q < 4; ++q){
        a0[q] += w*bf2f((u16)x0[q]);
        a1[q] += w*bf2f((u16)x1[q]);
      }
    }
  }
  {
    const u16* Xj = X + (size_t)wid*512;
    short4v x0 = *(const short4v*)(Xj + co0);
    short4v x1 = *(const short4v*)(Xj + co1);
    #pragma unroll
    for (int q = 0; q < 4; ++q){
      a0[q] += dj*bf2f((u16)x0[q]);
      a1[q] += dj*bf2f((u16)x1[q]);
    }
  }
  const float* Zj = Z + (size_t)wid*512;
  f32x4 b0 = *(const f32x4*)(Zj + co0) + (BETA_C*dj)*a0;
  f32x4 b1 = *(const f32x4*)(Zj + co1) + (BETA_C*dj)*a1;
  const u16* Pj = Xp + (size_t)wid*512;
  short4v p0 = *(const short4v*)(Pj + co0);
  short4v p1 = *(const short4v*)(Pj + co1);
  f32x4 v0, v1;
  #pragma unroll
  for (int q = 0; q < 4; ++q){
    v0[q] = om*b0[q] + (1.f-om)*bf2f((u16)p0[q]);
    v1[q] = om*b1[q] + (1.f-om)*bf2f((u16)p1[q]);
  }
  if constexpr (FIN){
    float d2 = dcv[wid];
    const u16* Uj = Ubf + (size_t)wid*512;
    short4v pk0, pk1;
    #pragma unroll
    for (int q = 0; q < 4; ++q){
      float x0 = d2*(v0[q] + d2*bf2f(Uj[co0 + q])) + bias[co0 + q];
      float pa0 = avec[co0 + q];
      float r0 = x0 >= 0.f ? x0 : pa0*x0;
      v0[q] = r0; pk0[q] = f2bf(r0);
      float x1 = d2*(v1[q] + d2*bf2f(Uj[co1 + q])) + bias[co1 + q];
      float pa1 = avec[co1 + q];
      float r1 = x1 >= 0.f ? x1 : pa1*x1;
      v1[q] = r1; pk1[q] = f2bf(r1);
    }
    float* oj = zo + (size_t)wid*512;
    u16* bj = zobf + (size_t)wid*512;
    *(f32x4*)(oj + co0) = v0;
    *(f32x4*)(oj + co1) = v1;
    *(short4v*)(bj + co0) = pk0;
    *(short4v*)(bj + co1) = pk1;
  } else {
    short4v w0, w1;
    #pragma unroll
    for (int q = 0; q < 4; ++q){ w0[q] = f2bf(v0[q]); w1[q] = f2bf(v1[q]); }
    u16* oj = Xn + (size_t)wid*512;
    *(short4v*)(oj + co0) = w0;
    *(short4v*)(oj + co1) = w1;
  }
}

// ---------- segment sum -> [NG, 1024] bf16 ----------
__global__ void k_segsum(const float* __restrict__ z1, const float* __restrict__ z2,
                         const int* __restrict__ gptr, u16* __restrict__ gv){
  int g = blockIdx.x, t = threadIdx.x;
  float s0 = 0, s1 = 0, s2 = 0, s3 = 0;
  int rb = gptr[g], re = gptr[g+1];
  for (int r = rb; r < re; ++r){
    s0 += z1[(size_t)r*HIDC + t];       s1 += z1[(size_t)r*HIDC + 256 + t];
    s2 += z2[(size_t)r*HIDC + t];       s3 += z2[(size_t)r*HIDC + 256 + t];
  }
  gv[g*1024 + t] = (u16)f2bf(s0); gv[g*1024 + 256 + t] = (u16)f2bf(s1);
  gv[g*1024 + 512 + t] = (u16)f2bf(s2); gv[g*1024 + 768 + t] = (u16)f2bf(s3);
}

// ---------- bf16 MFMA GEMM: XCD-swizzled, double-buffered 2-phase, global_load_lds ----------
// ADDM: 0 none, 1 f32 addm, 2 bf16 addm via zbh. DUAL: col<512 -> zbh bf16 (+bias), else Cb bf16 (+bias2, prelu ap2).
template<int BM, int BN, int ACT, int ADDM, int BIAS, int KC, int SPLIT, int ZOUT, int WF32, int WBF, int DUAL>
__global__ __launch_bounds__(256, 2) void k_gemm(
    const u16* __restrict__ A, const u16* __restrict__ Bt,
    float* __restrict__ C, u16* __restrict__ Cb,
    const float* __restrict__ bias, const float* __restrict__ ap,
    const float* __restrict__ addm, float* __restrict__ C2,
    float* __restrict__ zb, u16* __restrict__ zbh, const float* __restrict__ dcv,
    const float* __restrict__ bias2, const float* __restrict__ ap2,
    int M, int Nn, int K)
{
  __shared__ __align__(16) u16 As[2][BM*32];
  __shared__ __align__(16) u16 Bs[2][BN*32];
  const int tid = threadIdx.x;
  int nwg = gridDim.x * gridDim.y;
  int flat = blockIdx.y * gridDim.x + blockIdx.x;
  int swz = (flat & 7) * (nwg >> 3) + (flat >> 3);
  int bxx = swz % gridDim.x, byy = swz / gridDim.x;
  const int bm0 = byy*BM, bn0 = bxx*BN;
  const int lane = tid & 63, wv = tid >> 6;
  const int wr = wv >> 1, wc = wv & 1;
  constexpr int MR = BM/32, NR = BN/32;
  f32x4 acc[MR][NR];
  #pragma unroll
  for (int i = 0; i < MR; ++i)
    #pragma unroll
    for (int j = 0; j < NR; ++j) acc[i][j] = (f32x4){0.f,0.f,0.f,0.f};
  const int r0 = wr*(BM/2), c0 = wc*(BN/2);
  const int glr = lane >> 2, glc = (lane & 3)*8;
  int k0 = 0, k1 = K;
  if constexpr (KC > 0){ k0 = blockIdx.z*KC; k1 = k0 + KC; }
  const int nt = (k1 - k0) >> 5;
  auto STAGE = [&](int buf, int kt){
    #pragma unroll
    for (int q = 0; q < BM/64; ++q)
      gload16(A + (size_t)(bm0 + q*64 + wv*16 + glr)*K + kt + glc, &As[buf][(q*4+wv)*512]);
    #pragma unroll
    for (int q = 0; q < BN/64; ++q)
      gload16(Bt + (size_t)(bn0 + q*64 + wv*16 + glr)*K + kt + glc, &Bs[buf][(q*4+wv)*512]);
  };
  STAGE(0, k0);
  __syncthreads();
  for (int t = 0; t < nt; ++t){
    if (t + 1 < nt) STAGE((t+1)&1, k0 + ((t+1) << 5));
    short8 af[MR], bfv[NR];
    #pragma unroll
    for (int mi = 0; mi < MR; ++mi)
      af[mi] = *(const short8*)&As[t&1][(r0 + mi*16 + (lane & 15))*32 + (lane >> 4)*8];
    #pragma unroll
    for (int ni = 0; ni < NR; ++ni)
      bfv[ni] = *(const short8*)&Bs[t&1][(c0 + ni*16 + (lane & 15))*32 + (lane >> 4)*8];
    #pragma unroll
    for (int mi = 0; mi < MR; ++mi)
      #pragma unroll
      for (int ni = 0; ni < NR; ++ni)
        acc[mi][ni] = __builtin_amdgcn_mfma_f32_16x16x32_bf16(af[mi], bfv[ni], acc[mi][ni], 0, 0, 0);
    __syncthreads();
  }
  #pragma unroll
  for (int mi = 0; mi < MR; ++mi){
    #pragma unroll
    for (int ni = 0; ni < NR; ++ni){
      int col = bn0 + c0 + ni*16 + (lane & 15);
      #pragma unroll
      for (int q = 0; q < 4; ++q){
        int row = bm0 + r0 + mi*16 + ((lane >> 4) << 2) + q;
        float v = acc[mi][ni][q];
        if constexpr (KC > 0){
          C[(size_t)blockIdx.z*M*Nn + (size_t)row*Nn + col] = v;
        } else if constexpr (DUAL){
          if (col < 512){
            v += bias[col];
            zbh[(size_t)row*512 + col] = (u16)f2bf(v);
          } else {
            int c2 = col - 512;
            v += bias2[c2];
            float a = ap2[0];
            v = v >= 0.f ? v : a*v;
            Cb[(size_t)row*512 + c2] = (u16)f2bf(v);
          }
        } else {
          if constexpr (BIAS) v += bias[col];
          if constexpr (ACT == 1){ float a = ap[col]; v = v >= 0.f ? v : a*v; }
          if constexpr (ACT == 2){ float a = ap[0];   v = v >= 0.f ? v : a*v; }
          if constexpr (ADDM == 1) v += addm[(size_t)row*Nn + col];
          if constexpr (ADDM == 2) v += bf2f(zbh[(size_t)row*Nn + col]);
          if constexpr (WF32){
            if constexpr (SPLIT){
              float* dst = (row < NN) ? (C + (size_t)row*Nn) : (C2 + (size_t)(row - NN)*Nn);
              dst[col] = v;
            } else {
              C[(size_t)row*Nn + col] = v;
            }
          }
          if constexpr (WBF) Cb[(size_t)row*Nn + col] = (u16)f2bf(v);
          if constexpr (ZOUT){
            float zv = ALPHA_C * dcv[row] * v;
            zb[(size_t)row*Nn + col] = zv;
            zbh[(size_t)row*Nn + col] = (u16)f2bf(zv);
          }
        }
      }
    }
  }
}

// split-K reduce + epilogue. MODE 0: dual (gsb f32 | gh1 bf16+act); 1: bf16+act; 2: final split.
template<int MODE>
__global__ void k_red(const float* __restrict__ part, int KS, int Nn,
                      const float* __restrict__ b1, const float* __restrict__ a1s,
                      const float* __restrict__ b2, const float* __restrict__ a2s,
                      float* __restrict__ Cf, u16* __restrict__ Cb,
                      const float* __restrict__ addm,
                      float* __restrict__ o1, float* __restrict__ o2){
  int idx = blockIdx.x*256 + threadIdx.x;
  if (idx >= 128*Nn) return;
  float v = 0.f;
  for (int z = 0; z < KS; ++z) v += part[(size_t)z*128*Nn + idx];
  int row = idx / Nn, col = idx - row*Nn;
  if constexpr (MODE == 0){
    if (col < 512){
      v += b1[col];
      Cf[(size_t)row*512 + col] = v;
    } else {
      int c2 = col - 512;
      v += b2[c2];
      float a = a2s[0]; v = v >= 0.f ? v : a*v;
      Cb[(size_t)row*512 + c2] = (u16)f2bf(v);
    }
  } else if constexpr (MODE == 1){
    v += b1[col];
    float a = a1s[0]; v = v >= 0.f ? v : a*v;
    Cb[idx] = (u16)f2bf(v);
  } else {
    v += b1[col];
    float a = a1s[0]; v = v >= 0.f ? v : a*v;
    v += addm[idx];
    if (row < NG) o1[(size_t)row*Nn + col] = v;
    else o2[(size_t)(row - NG)*Nn + col] = v;
  }
}

extern "C" void kernel_launch(void* const* d_in, const int* in_sizes, int n_in,
                              void* d_out, int out_size, void* d_ws, size_t ws_size,
                              hipStream_t stream) {
  const float* cb   = (const float*)d_in[0];
  const float* g1W0 = (const float*)d_in[1];  const float* g1b0 = (const float*)d_in[2];
  const float* g1W1 = (const float*)d_in[3];  const float* g1b1 = (const float*)d_in[4];
  const float* g1a  = (const float*)d_in[5];
  const float* g2W0 = (const float*)d_in[6];  const float* g2b0 = (const float*)d_in[7];
  const float* g2W1 = (const float*)d_in[8];  const float* g2b1 = (const float*)d_in[9];
  const float* g2a  = (const float*)d_in[10];
  const float* m1W1 = (const float*)d_in[11]; const float* m1b1 = (const float*)d_in[12];
  const float* m1W2 = (const float*)d_in[13]; const float* m1b2 = (const float*)d_in[14];
  const float* m1W3 = (const float*)d_in[15]; const float* m1b3 = (const float*)d_in[16];
  const float* m1a1 = (const float*)d_in[17]; const float* m1a2 = (const float*)d_in[18];
  const float* m1a3 = (const float*)d_in[19];
  const float* m1Ws = (const float*)d_in[20]; const float* m1bs = (const float*)d_in[21];
  const float* m2W1 = (const float*)d_in[22]; const float* m2b1 = (const float*)d_in[23];
  const float* m2W2 = (const float*)d_in[24]; const float* m2b2 = (const float*)d_in[25];
  const float* m2W3 = (const float*)d_in[26]; const float* m2b3 = (const float*)d_in[27];
  const float* m2a1 = (const float*)d_in[28]; const float* m2a2 = (const float*)d_in[29];
  const float* m2a3 = (const float*)d_in[30];
  const float* m2Ws = (const float*)d_in[31]; const float* m2bs = (const float*)d_in[32];
  const int* xidx  = (const int*)d_in[33];
  const int* ei    = (const int*)d_in[34];
  const int* batch = (const int*)d_in[35];
  float* out = (float*)d_out;
  char* W = (char*)d_ws;
  constexpr size_t MB = 1024u*1024u;
  constexpr size_t KB = 1024u;

  // ---- workspace layout ----
  unsigned* Abits  = (unsigned*)(W);            // 0-2MB, dead after fill
  unsigned* ATbits = (unsigned*)(W + 2*MB);     // 2-4MB, dead after fill
  u16* w_g1W0t   = (u16*)(W);
  u16* w_g2W0t   = (u16*)(W + 128*KB);
  u16* w_g1W1t   = (u16*)(W + 256*KB);
  u16* w_g2W1t   = (u16*)(W + 768*KB);
  u16* w_m1WsW1t = (u16*)(W + 1280*KB);         // [1024,512] 1MB
  u16* w_m1W2t   = (u16*)(W + 2304*KB);
  u16* w_m1W3t   = (u16*)(W + 2816*KB);
  char* M4 = W + 4*MB;
  int* cntD  = (int*)(M4);
  int* cur   = (int*)(M4 + 16*KB);
  int* bcnt  = (int*)(M4 + 32*KB);
  int* cntAT = (int*)(M4 + 48*KB);
  int* rpAT  = (int*)(M4 + 80*KB);
  int* rpD   = (int*)(M4 + 100*KB);
  int* gptr  = (int*)(M4 + 120*KB);
  float* di  = (float*)(M4 + 124*KB);
  float* dis = (float*)(M4 + 140*KB);
  float* dc  = (float*)(M4 + 156*KB);
  float* wv0 = (float*)(M4 + 172*KB);
  float* wv1 = (float*)(M4 + 188*KB);
  float* sink = (float*)(M4 + 208*KB);          // 16KB dead scratch for k_warm
  int* colAT = (int*)(W + 4*MB + 256*KB);       // 256KB
  int* srcD  = (int*)(W + 4*MB + 512*KB);       // 256KB
  u16* gvbf  = (u16*)(W + 4*MB + 768*KB);       // [128,1024] 256KB
  u16* gh1bf = (u16*)(W + 5*MB);                // 128KB
  u16* gh2bf = (u16*)(W + 5*MB + 128*KB);       // 128KB
  float* gsb = (float*)(W + 5*MB + 256*KB);     // [128,512] 256KB
  float* xf  = (float*)(W + 6*MB);              // [4096,128] 2MB
  u16* xfbf  = (u16*)(W + 8*MB);                // 1MB
  u16* PxBf  = (u16*)(W + 9*MB);                // 1MB
  u16* w_m2WsW1t = (u16*)(W + 10*MB);           // [1024,1024] 2MB
  u16* w_m2W2t   = (u16*)(W + 12*MB);
  u16* w_m2W3t   = (u16*)(W + 12*MB + 512*KB);
  float* Zb128 = (float*)(W + 13*MB);           // 2MB
  float* Zb  = (float*)(W + 15*MB);             // 8MB f32 (dead after b512 chain)
  float* XA128 = (float*)(W + 23*MB);           // 2MB
  float* XB128 = (float*)(W + 25*MB);           // 2MB
  u16* Zbh  = (u16*)(W + 27*MB);                // 4MB bf16 Z (iter-1 gathers)
  u16* XAh  = (u16*)(W + 31*MB);                // 4MB bf16 b512 iterate
  u16* z1sbf = (u16*)(W + 35*MB);               // 4MB (dead before XBh chain use)
  u16* XBh  = (u16*)(W + 35*MB);                // 4MB bf16 b512 iterate (over z1sbf, disjoint)
  u16* Ubf   = (u16*)(W + 39*MB);               // 4MB
  float* z1s = (float*)(W + 43*MB);             // 8MB
  u16* zsbf  = (u16*)(W + 51*MB);               // [8192,512] 8MB
  u16* z21bf = zsbf;
  u16* z22bf = (u16*)(W + 55*MB);
  float* ztmp = (float*)(W + 59*MB);            // 8MB
  u16* sbh = (u16*)(W + 15*MB);                 // [8192,512] bf16 8MB over Zb (dead in MLP1)
  u16* h1  = (u16*)(W + 31*MB);                 // 8MB over XAh/XBh (dead after chain)
  u16* h2  = (u16*)(W + 59*MB);                 // over ztmp (dead after segsum2)
  float* gpart = (float*)(W + 59*MB);           // MLP2 partials <=4MB (h2 dead after MLP1)

  // Chebyshev omegas (sigma = 0.8 -> sigma^2/4 = 0.16)
  float omg[11];
  {
    double o = 1.0; omg[0] = 0.f; omg[1] = 1.0f;
    for (int k = 2; k <= 10; ++k){ o = 1.0/(1.0 - 0.16*o); omg[k] = (float)o; }
  }

  // ---- warm inputs into L3 + zero bitmaps/counters (replaces memsets) ----
  {
    WarmPack wp;
    wp.p[0] = cb;    wp.n4[0] = (BFD + 1)*CIN/4;      // 262176
    wp.p[1] = g1W0;  wp.n4[1] = 128*512/4;
    wp.p[2] = g2W0;  wp.n4[2] = 128*512/4;
    wp.p[3] = g1W1;  wp.n4[3] = 512*512/4;
    wp.p[4] = g2W1;  wp.n4[4] = 512*512/4;
    wp.p[5] = m1W1;  wp.n4[5] = 512*512/4;
    wp.p[6] = m1W2;  wp.n4[6] = 512*512/4;
    wp.p[7] = m1W3;  wp.n4[7] = 512*512/4;
    wp.p[8] = m1Ws;  wp.n4[8] = 512*512/4;
    wp.p[9] = m2W1;  wp.n4[9] = 1024*512/4;
    wp.p[10] = m2Ws; wp.n4[10] = 1024*512/4;
    wp.p[11] = m2W2; wp.n4[11] = 512*512/4;
    wp.p[12] = m2W3; wp.n4[12] = 512*512/4;
    wp.p[13] = (const float*)xidx;  wp.n4[13] = NN*NBAG/4;
    wp.p[14] = (const float*)ei;    wp.n4[14] = 2*NE/4;
    wp.p[15] = (const float*)batch; wp.n4[15] = NN/4;
    int zn4 = (int)((4*MB + 64*KB)/16);
    k_warm<<<2048, 256, 0, stream>>>(wp, (float*)W, zn4, sink);
  }

  k_prep0<<<2320, 256, 0, stream>>>(cb, xidx, xf, xfbf, ei, Abits, ATbits, cntD, batch, bcnt);
  k_popc2<<<2048, 256, 0, stream>>>(Abits, ATbits, di, cntAT);
  k_prefix3<<<3, 1024, 0, stream>>>(cntAT, rpAT, NN, cntD, rpD, NN, bcnt, gptr, NG, dis);
  {
    WPack p = {{ {g1W0, w_g1W0t, 128, 512}, {g2W0, w_g2W0t, 128, 512},
                 {g1W1, w_g1W1t, 512, 512}, {g2W1, w_g2W1t, 512, 512},
                 {m1Ws, w_m1WsW1t, 512, 512}, {m1W1, w_m1WsW1t + 512*512, 512, 512},
                 {m1W2, w_m1W2t, 512, 512}, {m1W3, w_m1W3t, 512, 512},
                 {m2Ws, w_m2WsW1t, 1024, 512}, {m2W1, w_m2WsW1t + 512*1024, 1024, 512},
                 {m2W2, w_m2W2t, 512, 512}, {m2W3, w_m2W3t, 512, 512} }};
    k_fillwconv<<<1280 + 6144, 256, 0, stream>>>(ATbits, rpAT, colAT, ei, rpD, cur, srcD, p);
  }

  // ---- tower 1 (sparse GCN), U staged as bf16 ----
  k_gemm<128,64,0,0,0,0,0,0,0,1,0><<<dim3(8, 32), 256, 0, stream>>>(
      xfbf, w_g1W0t, nullptr, Ubf, nullptr, nullptr, nullptr, nullptr, nullptr, nullptr, nullptr, nullptr, nullptr, NN, HIDC, CIN);
  k_gcn_sp<<<1024, 256, 0, stream>>>(Ubf, z1s, z1sbf, rpD, srcD, dis, g1b0, g1a);
  k_gemm<128,64,0,0,0,0,0,0,0,1,0><<<dim3(8, 32), 256, 0, stream>>>(
      z1sbf, w_g1W1t, nullptr, Ubf, nullptr, nullptr, nullptr, nullptr, nullptr, nullptr, nullptr, nullptr, nullptr, NN, HIDC, HIDC);
  k_gcn_sp<<<1024, 256, 0, stream>>>(Ubf, ztmp, z21bf, rpD, srcD, dis, g1b1, g1a);
  k_segsum<<<NG, 256, 0, stream>>>(z1s, ztmp, gptr, gvbf);

  // ---- w-solve -> dc (Chebyshev K=8); final step writes Zb128 = alpha*dc*xf ----
  k_wstep<0><<<1024, 256, 0, stream>>>(nullptr, nullptr, wv0, rpAT, colAT, di, nullptr, 1.0f, nullptr, nullptr);
  {
    float *curp = wv0, *prv = wv0;
    for (int k = 2; k < K_W; ++k){
      float* nxt = (k == 2) ? wv1 : (float*)prv;
      if (k == 2) prv = wv0;
      k_wstep<1><<<1024, 256, 0, stream>>>(curp, prv, nxt, rpAT, colAT, di, nullptr, omg[k], nullptr, nullptr);
      float* t = curp; curp = nxt; prv = t;
    }
    k_wstep<2><<<1024, 256, 0, stream>>>(curp, prv, nullptr, rpAT, colAT, di, dc, omg[K_W], xf, Zb128);
  }

  // ---- tower 2 layer 1: P@x (128 cols), Chebyshev f32, K=8 ----
  k_b128<0><<<1024, 256, 0, stream>>>(Zb128, Zb128, Zb128, XA128, nullptr, rpAT, colAT, di, 1.0f, nullptr, nullptr);
  {
    float *curp = XA128, *prv = Zb128;
    for (int k = 2; k < K_CH; ++k){
      float* nxt = (k == 2) ? XB128 : prv;
      k_b128<0><<<1024, 256, 0, stream>>>(curp, Zb128, prv, nxt, nullptr, rpAT, colAT, di, omg[k], nullptr, nullptr);
      prv = curp; curp = nxt;
    }
    k_b128<1><<<1024, 256, 0, stream>>>(curp, Zb128, prv, nullptr, PxBf, rpAT, colAT, di, omg[K_CH], dc, xf);
  }
  k_gemm<128,64,1,0,1,0,0,0,1,1,0><<<dim3(8, 32), 256, 0, stream>>>(
      PxBf, w_g2W0t, z1s, z1sbf, g2b0, g2a, nullptr, nullptr, nullptr, nullptr, nullptr, nullptr, nullptr, NN, HIDC, CIN);

  // ---- tower 2 layer 2: U = z1*W1 (bf16 + fused Z prep f32+bf16), then b512 chain (bf16, K=8) ----
  k_gemm<128,64,0,0,0,0,0,1,0,1,0><<<dim3(8, 32), 256, 0, stream>>>(
      z1sbf, w_g2W1t, nullptr, Ubf, nullptr, nullptr, nullptr, nullptr, Zb, Zbh, dc, nullptr, nullptr, NN, HIDC, HIDC);
  k_b512h<0><<<1024, 256, 0, stream>>>(Zbh, Zb, Zbh, XAh, nullptr, nullptr, rpAT, colAT, di, 1.0f, nullptr, nullptr, nullptr, nullptr);
  {
    u16 *curp = XAh, *prv = Zbh;
    for (int k = 2; k < K_CH; ++k){
      u16* nxt = (k == 2) ? XBh : prv;
      k_b512h<0><<<1024, 256, 0, stream>>>(curp, Zb, prv, nxt, nullptr, nullptr, rpAT, colAT, di, omg[k], nullptr, nullptr, nullptr, nullptr);
      prv = curp; curp = nxt;
    }
    k_b512h<1><<<1024, 256, 0, stream>>>(curp, Zb, prv, nullptr, ztmp, z22bf, rpAT, colAT, di, omg[K_CH], dc, Ubf, g2b1, g2a);
  }
  k_segsum<<<NG, 256, 0, stream>>>(z1s, ztmp, gptr, gvbf + 64*1024);

  // ---- MLP1 on stacked zsbf = [z21bf|z22bf], M=8192 (skip branch bf16 in sbh) ----
  k_gemm<128,64,0,0,0,0,0,0,0,0,1><<<dim3(16, 64), 256, 0, stream>>>(
      zsbf, w_m1WsW1t, nullptr, h1, m1bs, nullptr, nullptr, nullptr, nullptr, sbh, nullptr, m1b1, m1a1, 8192, 1024, HIDC);
  k_gemm<128,64,2,0,1,0,0,0,0,1,0><<<dim3(8, 64), 256, 0, stream>>>(
      h1, w_m1W2t, nullptr, h2, m1b2, m1a2, nullptr, nullptr, nullptr, nullptr, nullptr, nullptr, nullptr, 8192, HIDC, HIDC);
  k_gemm<128,64,2,2,1,0,1,0,1,0,0><<<dim3(8, 64), 256, 0, stream>>>(
      h2, w_m1W3t, out, nullptr, m1b3, m1a3, nullptr, out + 2129920, nullptr, sbh, nullptr, nullptr, nullptr, 8192, HIDC, HIDC);

  // ---- MLP2 on stacked gvbf [128,1024], split-K ----
  k_gemm<64,64,0,0,0,128,0,0,1,0,0><<<dim3(16, 2, 8), 256, 0, stream>>>(
      gvbf, w_m2WsW1t, gpart, nullptr, nullptr, nullptr, nullptr, nullptr, nullptr, nullptr, nullptr, nullptr, nullptr, 128, 1024, 1024);
  k_red<0><<<512, 256, 0, stream>>>(gpart, 8, 1024, m2bs, nullptr, m2b1, m2a1, gsb, gh1bf, nullptr, nullptr, nullptr);
  k_gemm<64,64,0,0,0,64,0,0,1,0,0><<<dim3(8, 2, 8), 256, 0, stream>>>(
      gh1bf, w_m2W2t, gpart, nullptr, nullptr, nullptr, nullptr, nullptr, nullptr, nullptr, nullptr, nullptr, nullptr, 128, HIDC, HIDC);
  k_red<1><<<256, 256, 0, stream>>>(gpart, 8, 512, m2b2, m2a2, nullptr, nullptr, nullptr, gh2bf, nullptr, nullptr, nullptr);
  k_gemm<64,64,0,0,0,64,0,0,1,0,0><<<dim3(8, 2, 8), 256, 0, stream>>>(
      gh2bf, w_m2W3t, gpart, nullptr, nullptr, nullptr, nullptr, nullptr, nullptr, nullptr, nullptr, nullptr, nullptr, 128, HIDC, HIDC);
  k_red<2><<<256, 256, 0, stream>>>(gpart, 8, 512, m2b3, m2a3, nullptr, nullptr, nullptr, nullptr, gsb, out + 2097152, out + 4227072);
}

// Round 14
// 450.794 us; speedup vs baseline: 1.0049x; 1.0049x over previous
//
#include <hip/hip_runtime.h>

// MVGRL encoder, MI355X gfx950. Round 14: drop dead warm reads (k_zero only); numerics identical to R12/13.
#define NN 4096
#define NE 65536
#define NBAG 16
#define BFD 8192
#define CIN 128
#define HIDC 512
#define NG 64
#define ALPHA_C 0.2f
#define BETA_C 0.8f
#define K_CH 8
#define K_W 8

typedef unsigned short u16;
typedef __attribute__((ext_vector_type(8))) short short8;
typedef __attribute__((ext_vector_type(4))) short short4v;
typedef __attribute__((ext_vector_type(4))) float f32x4;
typedef __attribute__((ext_vector_type(2))) float f32x2;

__device__ __forceinline__ short f2bf(float f){
  unsigned u = __float_as_uint(f);
  u += 0x7fffu + ((u >> 16) & 1u);
  return (short)(u >> 16);
}
__device__ __forceinline__ float bf2f(u16 h){
  return __uint_as_float(((unsigned)h) << 16);
}
__device__ __forceinline__ void gload16(const void* g, const void* l){
  __builtin_amdgcn_global_load_lds(
    (const __attribute__((address_space(1))) unsigned int*)g,
    (__attribute__((address_space(3))) unsigned int*)l, 16, 0, 0);
}

// ---------- workspace zeroing (bitmaps + counters) ----------
__global__ __launch_bounds__(256) void k_zero(float* __restrict__ zero0, int zn4){
  int gtid = blockIdx.x*256 + threadIdx.x, gsz = gridDim.x*256;
  f32x4 zv = {0,0,0,0};
  for (int i = gtid; i < zn4; i += gsz) ((f32x4*)zero0)[i] = zv;
}

// ---------- merged prep: embed | edge scatter | batch hist ----------
__global__ void k_prep0(const float* __restrict__ cb, const int* __restrict__ xidx,
                        float* __restrict__ xf, u16* __restrict__ xfbf,
                        const int* __restrict__ ei, unsigned* __restrict__ Ab,
                        unsigned* __restrict__ ATb, int* __restrict__ cntD,
                        const int* __restrict__ batch, int* __restrict__ bcnt){
  int bx = blockIdx.x;
  if (bx < 2048){
    int n = bx*2 + (threadIdx.x >> 7);
    int c = threadIdx.x & 127;
    float acc = 0.f; int cnt = 0;
    #pragma unroll
    for (int b = 0; b < NBAG; ++b){
      int id = xidx[n*NBAG + b];
      if (id != BFD){ acc += cb[(size_t)id*CIN + c]; ++cnt; }
    }
    float v = acc / (float)(cnt > 0 ? cnt : 1);
    xf[(size_t)n*CIN + c] = v;
    xfbf[(size_t)n*CIN + c] = (u16)f2bf(v);
  } else if (bx < 2304){
    int e = (bx - 2048)*256 + threadIdx.x;
    int s = ei[e], d = ei[NE + e];
    atomicOr(&Ab[s*128 + (d >> 5)], 1u << (d & 31));
    atomicOr(&ATb[d*128 + (s >> 5)], 1u << (s & 31));
    atomicAdd(&cntD[d], 1);
  } else {
    int n = (bx - 2304)*256 + threadIdx.x;
    if (n < NN) atomicAdd(&bcnt[batch[n]], 1);
  }
}

// popcount rows; A-side writes di directly, AT-side writes cntAT
__global__ void k_popc2(const unsigned* __restrict__ Ab, const unsigned* __restrict__ ATb,
                        float* __restrict__ di, int* __restrict__ cntAT){
  int wid = (blockIdx.x*blockDim.x + threadIdx.x) >> 6;
  int lane = threadIdx.x & 63;
  if (wid >= 2*NN) return;
  const unsigned* bits; int r;
  if (wid < NN){ bits = Ab; r = wid; }
  else { bits = ATb; r = wid - NN; }
  int s = __popc(bits[r*128 + lane]) + __popc(bits[r*128 + 64 + lane]);
  #pragma unroll
  for (int off = 32; off > 0; off >>= 1) s += __shfl_down(s, off);
  if (lane == 0){
    if (wid < NN) di[r] = rsqrtf((float)s + 1.0f);
    else cntAT[r] = s;
  }
}

// three exclusive prefix sums; block 1 also emits dis = rsqrt(cntD+1)
__global__ void k_prefix3(const int* __restrict__ c0, int* __restrict__ r0, int n0,
                          const int* __restrict__ c1, int* __restrict__ r1, int n1,
                          const int* __restrict__ c2, int* __restrict__ r2, int n2,
                          float* __restrict__ dis){
  const int* cnt; int* rp; int n;
  if (blockIdx.x == 0){ cnt = c0; rp = r0; n = n0; }
  else if (blockIdx.x == 1){ cnt = c1; rp = r1; n = n1; }
  else { cnt = c2; rp = r2; n = n2; }
  __shared__ int a[4096];
  __shared__ int ps[1024];
  int t = threadIdx.x;
  for (int i = t; i < 4096; i += 1024) a[i] = (i < n) ? cnt[i] : 0;
  __syncthreads();
  if (blockIdx.x == 1){
    for (int i = t; i < NN; i += 1024) dis[i] = rsqrtf((float)a[i] + 1.0f);
  }
  int b0 = a[t*4], b1 = a[t*4+1], b2 = a[t*4+2], b3 = a[t*4+3];
  int s0 = b0, s1 = s0+b1, s2 = s1+b2, s3 = s2+b3;
  ps[t] = s3;
  __syncthreads();
  for (int off = 1; off < 1024; off <<= 1){
    int v = ps[t];
    int u = (t >= off) ? ps[t-off] : 0;
    __syncthreads();
    ps[t] = v + u;
    __syncthreads();
  }
  int excl = (t > 0) ? ps[t-1] : 0;
  int base = t*4;
  if (base     < n) rp[base]   = excl;
  if (base + 1 < n) rp[base+1] = excl + s0;
  if (base + 2 < n) rp[base+2] = excl + s1;
  if (base + 3 < n) rp[base+3] = excl + s2;
  if (t == 1023) rp[n] = ps[1023];
}

// ---------- weight descriptors ----------
struct WDesc { const float* src; u16* dst; int K; int N; };
struct WPack { WDesc w[12]; };

// CSR fill + weight convert in one launch
__global__ void k_fillwconv(const unsigned* __restrict__ bits, const int* __restrict__ rpA,
                            int* __restrict__ colidx,
                            const int* __restrict__ ei, const int* __restrict__ rpD,
                            int* __restrict__ cur, int* __restrict__ srcs,
                            WPack p){
  int bx = blockIdx.x;
  if (bx < 1024){
    int wid = (bx*blockDim.x + threadIdx.x) >> 6;
    int lane = threadIdx.x & 63;
    unsigned w0 = bits[wid*128 + lane];
    unsigned w1 = bits[wid*128 + 64 + lane];
    int c = __popc(w0) + __popc(w1);
    int x = c;
    #pragma unroll
    for (int d = 1; d < 64; d <<= 1){
      int y = __shfl_up(x, d);
      if (lane >= d) x += y;
    }
    int pos = rpA[wid] + (x - c);
    while (w0){ int b = __ffs(w0) - 1; w0 &= w0 - 1; colidx[pos++] = lane*32 + b; }
    while (w1){ int b = __ffs(w1) - 1; w1 &= w1 - 1; colidx[pos++] = (64 + lane)*32 + b; }
  } else if (bx < 1280){
    int e = (bx - 1024)*256 + threadIdx.x;
    int s = ei[e], d = ei[NE + e];
    int pos = atomicAdd(&cur[d], 1);
    srcs[rpD[d] + pos] = s;
  } else {
    int t5 = bx - 1280;
    int z = t5 >> 9;
    int rem = t5 & 511;
    int ky = rem >> 4, nx = rem & 15;
    WDesc d = p.w[z];
    int k0 = ky*32, n0 = nx*32;
    if (k0 >= d.K || n0 >= d.N) return;
    __shared__ float t[32][33];
    int tx = threadIdx.x & 31, ty = threadIdx.x >> 5;
    #pragma unroll
    for (int r = 0; r < 4; ++r){
      int row = ty + r*8;
      t[row][tx] = d.src[(size_t)(k0 + row)*d.N + n0 + tx];
    }
    __syncthreads();
    #pragma unroll
    for (int r = 0; r < 4; ++r){
      int row = ty + r*8;
      d.dst[(size_t)(n0 + row)*d.K + k0 + tx] = (u16)f2bf(t[tx][row]);
    }
  }
}

// ---------- sparse-tower GCN aggregation (wave per row, shuffle-broadcast, bf16 U) ----------
__global__ __launch_bounds__(256) void k_gcn_sp(const u16* __restrict__ U, float* __restrict__ out,
    u16* __restrict__ outbf,
    const int* __restrict__ rp, const int* __restrict__ srcs, const float* __restrict__ dis,
    const float* __restrict__ bias, const float* __restrict__ avec){
  int wid = (blockIdx.x*256 + threadIdx.x) >> 6;
  int lane = threadIdx.x & 63;
  if (wid >= NN) return;
  int j = wid;
  f32x4 a0 = {0,0,0,0}, a1 = {0,0,0,0};
  int b = rp[j], e = rp[j+1];
  for (int base = b; base < e; base += 64){
    int idx = base + lane;
    int myc = 0; float myd = 0.f;
    if (idx < e){ myc = srcs[idx]; myd = dis[myc]; }
    int m = min(64, e - base);
    for (int k = 0; k < m; ++k){
      int s = __shfl(myc, k); float w = __shfl(myd, k);
      const u16* Us = U + (size_t)s*HIDC;
      short4v q0 = *(const short4v*)(Us + lane*4);
      short4v q1 = *(const short4v*)(Us + 256 + lane*4);
      #pragma unroll
      for (int r = 0; r < 4; ++r){
        a0[r] += w*bf2f((u16)q0[r]);
        a1[r] += w*bf2f((u16)q1[r]);
      }
    }
  }
  float dj = dis[j];
  const u16* Uj = U + (size_t)j*HIDC;
  short4v s0 = *(const short4v*)(Uj + lane*4);
  short4v s1 = *(const short4v*)(Uj + 256 + lane*4);
  #pragma unroll
  for (int r = 0; r < 4; ++r){
    a0[r] += dj*bf2f((u16)s0[r]);
    a1[r] += dj*bf2f((u16)s1[r]);
  }
  float* op = out + (size_t)j*HIDC;
  u16* ob = outbf + (size_t)j*HIDC;
  #pragma unroll
  for (int v = 0; v < 4; ++v){
    int c0 = lane*4 + v, c1 = 256 + lane*4 + v;
    float x0 = dj*a0[v] + bias[c0]; float p0 = avec[c0];
    float r0 = x0 >= 0.f ? x0 : p0*x0;
    op[c0] = r0; ob[c0] = (u16)f2bf(r0);
    float x1 = dj*a1[v] + bias[c1]; float p1 = avec[c1];
    float r1 = x1 >= 0.f ? x1 : p1*x1;
    op[c1] = r1; ob[c1] = (u16)f2bf(r1);
  }
}

// ---------- Chebyshev w-step. MODE 0: first; 1: mid; 2: final -> dc + fused Z prep ----------
template<int MODE>
__global__ __launch_bounds__(256) void k_wstep(const float* __restrict__ w, const float* wp,
    float* __restrict__ wn, const int* __restrict__ rp, const int* __restrict__ cols,
    const float* __restrict__ di, float* __restrict__ dcv, float om,
    const float* __restrict__ xf, float* __restrict__ Zb128){
  int wid = (blockIdx.x*256 + threadIdx.x) >> 6;
  int lane = threadIdx.x & 63;
  if (wid >= NN) return;
  int b = rp[wid], e = rp[wid+1];
  float acc = 0.f;
  for (int k = b + lane; k < e; k += 64){
    int i = cols[k];
    float wi = (MODE == 0) ? ALPHA_C : w[i];
    acc += di[i]*wi;
  }
  #pragma unroll
  for (int o = 32; o > 0; o >>= 1) acc += __shfl_xor(acc, o);
  float dj = di[wid];
  float wj = (MODE == 0) ? ALPHA_C : w[wid];
  float basic = ALPHA_C + BETA_C*dj*(acc + dj*wj);
  float v = (MODE == 0) ? basic : (om*basic + (1.f - om)*wp[wid]);
  if (MODE == 2){
    float d2 = rsqrtf(fmaxf(v + 1.0f, 1e-12f));
    if (lane == 0) dcv[wid] = d2;
    f32x2 xv = *(const f32x2*)(xf + (size_t)wid*128 + lane*2);
    f32x2 z; z[0] = ALPHA_C*d2*xv[0]; z[1] = ALPHA_C*d2*xv[1];
    *(f32x2*)(Zb128 + (size_t)wid*128 + lane*2) = z;
  } else {
    if (lane == 0) wn[wid] = v;
  }
}

// ---------- Chebyshev step C=128, wave per row, shuffle-broadcast (f32) ----------
template<int FIN>
__global__ __launch_bounds__(256) void k_b128(const float* __restrict__ X, const float* __restrict__ Z,
    const float* Xp, float* Xn, u16* __restrict__ Pxbf,
    const int* __restrict__ rp, const int* __restrict__ cols,
    const float* __restrict__ di, float om,
    const float* __restrict__ dcv, const float* __restrict__ xf){
  int wid = (blockIdx.x*256 + threadIdx.x) >> 6;
  int lane = threadIdx.x & 63;
  if (wid >= NN) return;
  int j = wid;
  int b = rp[j], e = rp[j+1];
  float dj = di[j];
  f32x2 a0 = {0,0};
  for (int base = b; base < e; base += 64){
    int idx = base + lane;
    int myc = 0; float myd = 0.f;
    if (idx < e){ myc = cols[idx]; myd = di[myc]; }
    int m = min(64, e - base);
    for (int k = 0; k < m; ++k){
      int i = __shfl(myc, k); float w = __shfl(myd, k);
      a0 += w * (*(const f32x2*)(X + (size_t)i*128 + lane*2));
    }
  }
  a0 += dj * (*(const f32x2*)(X + (size_t)j*128 + lane*2));
  f32x2 basic = *(const f32x2*)(Z + (size_t)j*128 + lane*2) + (BETA_C*dj)*a0;
  f32x2 xp = *(const f32x2*)(Xp + (size_t)j*128 + lane*2);
  f32x2 v; v[0] = om*basic[0] + (1.f-om)*xp[0]; v[1] = om*basic[1] + (1.f-om)*xp[1];
  if constexpr (FIN){
    float d2 = dcv[j];
    f32x2 fv = *(const f32x2*)(xf + (size_t)j*128 + lane*2);
    unsigned pk = (unsigned)(unsigned short)f2bf(d2*(v[0] + d2*fv[0]))
                | ((unsigned)(unsigned short)f2bf(d2*(v[1] + d2*fv[1])) << 16);
    *(unsigned*)(Pxbf + (size_t)j*128 + lane*2) = pk;
  } else {
    *(f32x2*)(Xn + (size_t)j*128 + lane*2) = v;
  }
}

// ---------- Chebyshev step C=512, bf16 iterates, 1 wave/row dual-half ----------
template<int FIN>
__global__ __launch_bounds__(256) void k_b512h(const u16* __restrict__ X, const float* __restrict__ Z,
    const u16* Xp, u16* Xn, float* __restrict__ zo, u16* __restrict__ zobf,
    const int* __restrict__ rp, const int* __restrict__ cols,
    const float* __restrict__ di, float om,
    const float* __restrict__ dcv, const u16* __restrict__ Ubf,
    const float* __restrict__ bias, const float* __restrict__ avec){
  int wid = (blockIdx.x*256 + threadIdx.x) >> 6;
  int lane = threadIdx.x & 63;
  if (wid >= NN) return;
  int b = rp[wid], e = rp[wid+1];
  float dj = di[wid];
  const int co0 = lane*4, co1 = 256 + lane*4;
  f32x4 a0 = {0,0,0,0}, a1 = {0,0,0,0};
  for (int base = b; base < e; base += 64){
    int idx = base + lane;
    int myc = 0; float myd = 0.f;
    if (idx < e){ myc = cols[idx]; myd = di[myc]; }
    int m = min(64, e - base);
    for (int k = 0; k < m; ++k){
      int i = __shfl(myc, k); float w = __shfl(myd, k);
      const u16* Xi = X + (size_t)i*512;
      short4v x0 = *(const short4v*)(Xi + co0);
      short4v x1 = *(const short4v*)(Xi + co1);
      #pragma unroll
      for (int q = 0; q < 4; ++q){
        a0[q] += w*bf2f((u16)x0[q]);
        a1[q] += w*bf2f((u16)x1[q]);
      }
    }
  }
  {
    const u16* Xj = X + (size_t)wid*512;
    short4v x0 = *(const short4v*)(Xj + co0);
    short4v x1 = *(const short4v*)(Xj + co1);
    #pragma unroll
    for (int q = 0; q < 4; ++q){
      a0[q] += dj*bf2f((u16)x0[q]);
      a1[q] += dj*bf2f((u16)x1[q]);
    }
  }
  const float* Zj = Z + (size_t)wid*512;
  f32x4 b0 = *(const f32x4*)(Zj + co0) + (BETA_C*dj)*a0;
  f32x4 b1 = *(const f32x4*)(Zj + co1) + (BETA_C*dj)*a1;
  const u16* Pj = Xp + (size_t)wid*512;
  short4v p0 = *(const short4v*)(Pj + co0);
  short4v p1 = *(const short4v*)(Pj + co1);
  f32x4 v0, v1;
  #pragma unroll
  for (int q = 0; q < 4; ++q){
    v0[q] = om*b0[q] + (1.f-om)*bf2f((u16)p0[q]);
    v1[q] = om*b1[q] + (1.f-om)*bf2f((u16)p1[q]);
  }
  if constexpr (FIN){
    float d2 = dcv[wid];
    const u16* Uj = Ubf + (size_t)wid*512;
    short4v pk0, pk1;
    #pragma unroll
    for (int q = 0; q < 4; ++q){
      float x0 = d2*(v0[q] + d2*bf2f(Uj[co0 + q])) + bias[co0 + q];
      float pa0 = avec[co0 + q];
      float r0 = x0 >= 0.f ? x0 : pa0*x0;
      v0[q] = r0; pk0[q] = f2bf(r0);
      float x1 = d2*(v1[q] + d2*bf2f(Uj[co1 + q])) + bias[co1 + q];
      float pa1 = avec[co1 + q];
      float r1 = x1 >= 0.f ? x1 : pa1*x1;
      v1[q] = r1; pk1[q] = f2bf(r1);
    }
    float* oj = zo + (size_t)wid*512;
    u16* bj = zobf + (size_t)wid*512;
    *(f32x4*)(oj + co0) = v0;
    *(f32x4*)(oj + co1) = v1;
    *(short4v*)(bj + co0) = pk0;
    *(short4v*)(bj + co1) = pk1;
  } else {
    short4v w0, w1;
    #pragma unroll
    for (int q = 0; q < 4; ++q){ w0[q] = f2bf(v0[q]); w1[q] = f2bf(v1[q]); }
    u16* oj = Xn + (size_t)wid*512;
    *(short4v*)(oj + co0) = w0;
    *(short4v*)(oj + co1) = w1;
  }
}

// ---------- segment sum -> [NG, 1024] bf16 ----------
__global__ void k_segsum(const float* __restrict__ z1, const float* __restrict__ z2,
                         const int* __restrict__ gptr, u16* __restrict__ gv){
  int g = blockIdx.x, t = threadIdx.x;
  float s0 = 0, s1 = 0, s2 = 0, s3 = 0;
  int rb = gptr[g], re = gptr[g+1];
  for (int r = rb; r < re; ++r){
    s0 += z1[(size_t)r*HIDC + t];       s1 += z1[(size_t)r*HIDC + 256 + t];
    s2 += z2[(size_t)r*HIDC + t];       s3 += z2[(size_t)r*HIDC + 256 + t];
  }
  gv[g*1024 + t] = (u16)f2bf(s0); gv[g*1024 + 256 + t] = (u16)f2bf(s1);
  gv[g*1024 + 512 + t] = (u16)f2bf(s2); gv[g*1024 + 768 + t] = (u16)f2bf(s3);
}

// ---------- bf16 MFMA GEMM: XCD-swizzled, double-buffered 2-phase, global_load_lds ----------
// ADDM: 0 none, 1 f32 addm, 2 bf16 addm via zbh. DUAL: col<512 -> zbh bf16 (+bias), else Cb bf16 (+bias2, prelu ap2).
template<int BM, int BN, int ACT, int ADDM, int BIAS, int KC, int SPLIT, int ZOUT, int WF32, int WBF, int DUAL>
__global__ __launch_bounds__(256, 2) void k_gemm(
    const u16* __restrict__ A, const u16* __restrict__ Bt,
    float* __restrict__ C, u16* __restrict__ Cb,
    const float* __restrict__ bias, const float* __restrict__ ap,
    const float* __restrict__ addm, float* __restrict__ C2,
    float* __restrict__ zb, u16* __restrict__ zbh, const float* __restrict__ dcv,
    const float* __restrict__ bias2, const float* __restrict__ ap2,
    int M, int Nn, int K)
{
  __shared__ __align__(16) u16 As[2][BM*32];
  __shared__ __align__(16) u16 Bs[2][BN*32];
  const int tid = threadIdx.x;
  int nwg = gridDim.x * gridDim.y;
  int flat = blockIdx.y * gridDim.x + blockIdx.x;
  int swz = (flat & 7) * (nwg >> 3) + (flat >> 3);
  int bxx = swz % gridDim.x, byy = swz / gridDim.x;
  const int bm0 = byy*BM, bn0 = bxx*BN;
  const int lane = tid & 63, wv = tid >> 6;
  const int wr = wv >> 1, wc = wv & 1;
  constexpr int MR = BM/32, NR = BN/32;
  f32x4 acc[MR][NR];
  #pragma unroll
  for (int i = 0; i < MR; ++i)
    #pragma unroll
    for (int j = 0; j < NR; ++j) acc[i][j] = (f32x4){0.f,0.f,0.f,0.f};
  const int r0 = wr*(BM/2), c0 = wc*(BN/2);
  const int glr = lane >> 2, glc = (lane & 3)*8;
  int k0 = 0, k1 = K;
  if constexpr (KC > 0){ k0 = blockIdx.z*KC; k1 = k0 + KC; }
  const int nt = (k1 - k0) >> 5;
  auto STAGE = [&](int buf, int kt){
    #pragma unroll
    for (int q = 0; q < BM/64; ++q)
      gload16(A + (size_t)(bm0 + q*64 + wv*16 + glr)*K + kt + glc, &As[buf][(q*4+wv)*512]);
    #pragma unroll
    for (int q = 0; q < BN/64; ++q)
      gload16(Bt + (size_t)(bn0 + q*64 + wv*16 + glr)*K + kt + glc, &Bs[buf][(q*4+wv)*512]);
  };
  STAGE(0, k0);
  __syncthreads();
  for (int t = 0; t < nt; ++t){
    if (t + 1 < nt) STAGE((t+1)&1, k0 + ((t+1) << 5));
    short8 af[MR], bfv[NR];
    #pragma unroll
    for (int mi = 0; mi < MR; ++mi)
      af[mi] = *(const short8*)&As[t&1][(r0 + mi*16 + (lane & 15))*32 + (lane >> 4)*8];
    #pragma unroll
    for (int ni = 0; ni < NR; ++ni)
      bfv[ni] = *(const short8*)&Bs[t&1][(c0 + ni*16 + (lane & 15))*32 + (lane >> 4)*8];
    #pragma unroll
    for (int mi = 0; mi < MR; ++mi)
      #pragma unroll
      for (int ni = 0; ni < NR; ++ni)
        acc[mi][ni] = __builtin_amdgcn_mfma_f32_16x16x32_bf16(af[mi], bfv[ni], acc[mi][ni], 0, 0, 0);
    __syncthreads();
  }
  #pragma unroll
  for (int mi = 0; mi < MR; ++mi){
    #pragma unroll
    for (int ni = 0; ni < NR; ++ni){
      int col = bn0 + c0 + ni*16 + (lane & 15);
      #pragma unroll
      for (int q = 0; q < 4; ++q){
        int row = bm0 + r0 + mi*16 + ((lane >> 4) << 2) + q;
        float v = acc[mi][ni][q];
        if constexpr (KC > 0){
          C[(size_t)blockIdx.z*M*Nn + (size_t)row*Nn + col] = v;
        } else if constexpr (DUAL){
          if (col < 512){
            v += bias[col];
            zbh[(size_t)row*512 + col] = (u16)f2bf(v);
          } else {
            int c2 = col - 512;
            v += bias2[c2];
            float a = ap2[0];
            v = v >= 0.f ? v : a*v;
            Cb[(size_t)row*512 + c2] = (u16)f2bf(v);
          }
        } else {
          if constexpr (BIAS) v += bias[col];
          if constexpr (ACT == 1){ float a = ap[col]; v = v >= 0.f ? v : a*v; }
          if constexpr (ACT == 2){ float a = ap[0];   v = v >= 0.f ? v : a*v; }
          if constexpr (ADDM == 1) v += addm[(size_t)row*Nn + col];
          if constexpr (ADDM == 2) v += bf2f(zbh[(size_t)row*Nn + col]);
          if constexpr (WF32){
            if constexpr (SPLIT){
              float* dst = (row < NN) ? (C + (size_t)row*Nn) : (C2 + (size_t)(row - NN)*Nn);
              dst[col] = v;
            } else {
              C[(size_t)row*Nn + col] = v;
            }
          }
          if constexpr (WBF) Cb[(size_t)row*Nn + col] = (u16)f2bf(v);
          if constexpr (ZOUT){
            float zv = ALPHA_C * dcv[row] * v;
            zb[(size_t)row*Nn + col] = zv;
            zbh[(size_t)row*Nn + col] = (u16)f2bf(zv);
          }
        }
      }
    }
  }
}

// split-K reduce + epilogue. MODE 0: dual (gsb f32 | gh1 bf16+act); 1: bf16+act; 2: final split.
template<int MODE>
__global__ void k_red(const float* __restrict__ part, int KS, int Nn,
                      const float* __restrict__ b1, const float* __restrict__ a1s,
                      const float* __restrict__ b2, const float* __restrict__ a2s,
                      float* __restrict__ Cf, u16* __restrict__ Cb,
                      const float* __restrict__ addm,
                      float* __restrict__ o1, float* __restrict__ o2){
  int idx = blockIdx.x*256 + threadIdx.x;
  if (idx >= 128*Nn) return;
  float v = 0.f;
  for (int z = 0; z < KS; ++z) v += part[(size_t)z*128*Nn + idx];
  int row = idx / Nn, col = idx - row*Nn;
  if constexpr (MODE == 0){
    if (col < 512){
      v += b1[col];
      Cf[(size_t)row*512 + col] = v;
    } else {
      int c2 = col - 512;
      v += b2[c2];
      float a = a2s[0]; v = v >= 0.f ? v : a*v;
      Cb[(size_t)row*512 + c2] = (u16)f2bf(v);
    }
  } else if constexpr (MODE == 1){
    v += b1[col];
    float a = a1s[0]; v = v >= 0.f ? v : a*v;
    Cb[idx] = (u16)f2bf(v);
  } else {
    v += b1[col];
    float a = a1s[0]; v = v >= 0.f ? v : a*v;
    v += addm[idx];
    if (row < NG) o1[(size_t)row*Nn + col] = v;
    else o2[(size_t)(row - NG)*Nn + col] = v;
  }
}

extern "C" void kernel_launch(void* const* d_in, const int* in_sizes, int n_in,
                              void* d_out, int out_size, void* d_ws, size_t ws_size,
                              hipStream_t stream) {
  const float* cb   = (const float*)d_in[0];
  const float* g1W0 = (const float*)d_in[1];  const float* g1b0 = (const float*)d_in[2];
  const float* g1W1 = (const float*)d_in[3];  const float* g1b1 = (const float*)d_in[4];
  const float* g1a  = (const float*)d_in[5];
  const float* g2W0 = (const float*)d_in[6];  const float* g2b0 = (const float*)d_in[7];
  const float* g2W1 = (const float*)d_in[8];  const float* g2b1 = (const float*)d_in[9];
  const float* g2a  = (const float*)d_in[10];
  const float* m1W1 = (const float*)d_in[11]; const float* m1b1 = (const float*)d_in[12];
  const float* m1W2 = (const float*)d_in[13]; const float* m1b2 = (const float*)d_in[14];
  const float* m1W3 = (const float*)d_in[15]; const float* m1b3 = (const float*)d_in[16];
  const float* m1a1 = (const float*)d_in[17]; const float* m1a2 = (const float*)d_in[18];
  const float* m1a3 = (const float*)d_in[19];
  const float* m1Ws = (const float*)d_in[20]; const float* m1bs = (const float*)d_in[21];
  const float* m2W1 = (const float*)d_in[22]; const float* m2b1 = (const float*)d_in[23];
  const float* m2W2 = (const float*)d_in[24]; const float* m2b2 = (const float*)d_in[25];
  const float* m2W3 = (const float*)d_in[26]; const float* m2b3 = (const float*)d_in[27];
  const float* m2a1 = (const float*)d_in[28]; const float* m2a2 = (const float*)d_in[29];
  const float* m2a3 = (const float*)d_in[30];
  const float* m2Ws = (const float*)d_in[31]; const float* m2bs = (const float*)d_in[32];
  const int* xidx  = (const int*)d_in[33];
  const int* ei    = (const int*)d_in[34];
  const int* batch = (const int*)d_in[35];
  float* out = (float*)d_out;
  char* W = (char*)d_ws;
  constexpr size_t MB = 1024u*1024u;
  constexpr size_t KB = 1024u;

  // ---- workspace layout ----
  unsigned* Abits  = (unsigned*)(W);            // 0-2MB, dead after fill
  unsigned* ATbits = (unsigned*)(W + 2*MB);     // 2-4MB, dead after fill
  u16* w_g1W0t   = (u16*)(W);
  u16* w_g2W0t   = (u16*)(W + 128*KB);
  u16* w_g1W1t   = (u16*)(W + 256*KB);
  u16* w_g2W1t   = (u16*)(W + 768*KB);
  u16* w_m1WsW1t = (u16*)(W + 1280*KB);         // [1024,512] 1MB
  u16* w_m1W2t   = (u16*)(W + 2304*KB);
  u16* w_m1W3t   = (u16*)(W + 2816*KB);
  char* M4 = W + 4*MB;
  int* cntD  = (int*)(M4);
  int* cur   = (int*)(M4 + 16*KB);
  int* bcnt  = (int*)(M4 + 32*KB);
  int* cntAT = (int*)(M4 + 48*KB);
  int* rpAT  = (int*)(M4 + 80*KB);
  int* rpD   = (int*)(M4 + 100*KB);
  int* gptr  = (int*)(M4 + 120*KB);
  float* di  = (float*)(M4 + 124*KB);
  float* dis = (float*)(M4 + 140*KB);
  float* dc  = (float*)(M4 + 156*KB);
  float* wv0 = (float*)(M4 + 172*KB);
  float* wv1 = (float*)(M4 + 188*KB);
  int* colAT = (int*)(W + 4*MB + 256*KB);       // 256KB
  int* srcD  = (int*)(W + 4*MB + 512*KB);       // 256KB
  u16* gvbf  = (u16*)(W + 4*MB + 768*KB);       // [128,1024] 256KB
  u16* gh1bf = (u16*)(W + 5*MB);                // 128KB
  u16* gh2bf = (u16*)(W + 5*MB + 128*KB);       // 128KB
  float* gsb = (float*)(W + 5*MB + 256*KB);     // [128,512] 256KB
  float* xf  = (float*)(W + 6*MB);              // [4096,128] 2MB
  u16* xfbf  = (u16*)(W + 8*MB);                // 1MB
  u16* PxBf  = (u16*)(W + 9*MB);                // 1MB
  u16* w_m2WsW1t = (u16*)(W + 10*MB);           // [1024,1024] 2MB
  u16* w_m2W2t   = (u16*)(W + 12*MB);
  u16* w_m2W3t   = (u16*)(W + 12*MB + 512*KB);
  float* Zb128 = (float*)(W + 13*MB);           // 2MB
  float* Zb  = (float*)(W + 15*MB);             // 8MB f32 (dead after b512 chain)
  float* XA128 = (float*)(W + 23*MB);           // 2MB
  float* XB128 = (float*)(W + 25*MB);           // 2MB
  u16* Zbh  = (u16*)(W + 27*MB);                // 4MB bf16 Z (iter-1 gathers)
  u16* XAh  = (u16*)(W + 31*MB);                // 4MB bf16 b512 iterate
  u16* z1sbf = (u16*)(W + 35*MB);               // 4MB (dead before XBh chain use)
  u16* XBh  = (u16*)(W + 35*MB);                // 4MB bf16 b512 iterate (over z1sbf, disjoint)
  u16* Ubf   = (u16*)(W + 39*MB);               // 4MB
  float* z1s = (float*)(W + 43*MB);             // 8MB
  u16* zsbf  = (u16*)(W + 51*MB);               // [8192,512] 8MB
  u16* z21bf = zsbf;
  u16* z22bf = (u16*)(W + 55*MB);
  float* ztmp = (float*)(W + 59*MB);            // 8MB
  u16* sbh = (u16*)(W + 15*MB);                 // [8192,512] bf16 8MB over Zb (dead in MLP1)
  u16* h1  = (u16*)(W + 31*MB);                 // 8MB over XAh/XBh (dead after chain)
  u16* h2  = (u16*)(W + 59*MB);                 // over ztmp (dead after segsum2)
  float* gpart = (float*)(W + 59*MB);           // MLP2 partials <=4MB (h2 dead after MLP1)

  // Chebyshev omegas (sigma = 0.8 -> sigma^2/4 = 0.16)
  float omg[11];
  {
    double o = 1.0; omg[0] = 0.f; omg[1] = 1.0f;
    for (int k = 2; k <= 10; ++k){ o = 1.0/(1.0 - 0.16*o); omg[k] = (float)o; }
  }

  // ---- zero bitmaps/counters ----
  {
    int zn4 = (int)((4*MB + 64*KB)/16);
    k_zero<<<1040, 256, 0, stream>>>((float*)W, zn4);
  }

  k_prep0<<<2320, 256, 0, stream>>>(cb, xidx, xf, xfbf, ei, Abits, ATbits, cntD, batch, bcnt);
  k_popc2<<<2048, 256, 0, stream>>>(Abits, ATbits, di, cntAT);
  k_prefix3<<<3, 1024, 0, stream>>>(cntAT, rpAT, NN, cntD, rpD, NN, bcnt, gptr, NG, dis);
  {
    WPack p = {{ {g1W0, w_g1W0t, 128, 512}, {g2W0, w_g2W0t, 128, 512},
                 {g1W1, w_g1W1t, 512, 512}, {g2W1, w_g2W1t, 512, 512},
                 {m1Ws, w_m1WsW1t, 512, 512}, {m1W1, w_m1WsW1t + 512*512, 512, 512},
                 {m1W2, w_m1W2t, 512, 512}, {m1W3, w_m1W3t, 512, 512},
                 {m2Ws, w_m2WsW1t, 1024, 512}, {m2W1, w_m2WsW1t + 512*1024, 1024, 512},
                 {m2W2, w_m2W2t, 512, 512}, {m2W3, w_m2W3t, 512, 512} }};
    k_fillwconv<<<1280 + 6144, 256, 0, stream>>>(ATbits, rpAT, colAT, ei, rpD, cur, srcD, p);
  }

  // ---- tower 1 (sparse GCN), U staged as bf16 ----
  k_gemm<128,64,0,0,0,0,0,0,0,1,0><<<dim3(8, 32), 256, 0, stream>>>(
      xfbf, w_g1W0t, nullptr, Ubf, nullptr, nullptr, nullptr, nullptr, nullptr, nullptr, nullptr, nullptr, nullptr, NN, HIDC, CIN);
  k_gcn_sp<<<1024, 256, 0, stream>>>(Ubf, z1s, z1sbf, rpD, srcD, dis, g1b0, g1a);
  k_gemm<128,64,0,0,0,0,0,0,0,1,0><<<dim3(8, 32), 256, 0, stream>>>(
      z1sbf, w_g1W1t, nullptr, Ubf, nullptr, nullptr, nullptr, nullptr, nullptr, nullptr, nullptr, nullptr, nullptr, NN, HIDC, HIDC);
  k_gcn_sp<<<1024, 256, 0, stream>>>(Ubf, ztmp, z21bf, rpD, srcD, dis, g1b1, g1a);
  k_segsum<<<NG, 256, 0, stream>>>(z1s, ztmp, gptr, gvbf);

  // ---- w-solve -> dc (Chebyshev K=8); final step writes Zb128 = alpha*dc*xf ----
  k_wstep<0><<<1024, 256, 0, stream>>>(nullptr, nullptr, wv0, rpAT, colAT, di, nullptr, 1.0f, nullptr, nullptr);
  {
    float *curp = wv0, *prv = wv0;
    for (int k = 2; k < K_W; ++k){
      float* nxt = (k == 2) ? wv1 : (float*)prv;
      if (k == 2) prv = wv0;
      k_wstep<1><<<1024, 256, 0, stream>>>(curp, prv, nxt, rpAT, colAT, di, nullptr, omg[k], nullptr, nullptr);
      float* t = curp; curp = nxt; prv = t;
    }
    k_wstep<2><<<1024, 256, 0, stream>>>(curp, prv, nullptr, rpAT, colAT, di, dc, omg[K_W], xf, Zb128);
  }

  // ---- tower 2 layer 1: P@x (128 cols), Chebyshev f32, K=8 ----
  k_b128<0><<<1024, 256, 0, stream>>>(Zb128, Zb128, Zb128, XA128, nullptr, rpAT, colAT, di, 1.0f, nullptr, nullptr);
  {
    float *curp = XA128, *prv = Zb128;
    for (int k = 2; k < K_CH; ++k){
      float* nxt = (k == 2) ? XB128 : prv;
      k_b128<0><<<1024, 256, 0, stream>>>(curp, Zb128, prv, nxt, nullptr, rpAT, colAT, di, omg[k], nullptr, nullptr);
      prv = curp; curp = nxt;
    }
    k_b128<1><<<1024, 256, 0, stream>>>(curp, Zb128, prv, nullptr, PxBf, rpAT, colAT, di, omg[K_CH], dc, xf);
  }
  k_gemm<128,64,1,0,1,0,0,0,1,1,0><<<dim3(8, 32), 256, 0, stream>>>(
      PxBf, w_g2W0t, z1s, z1sbf, g2b0, g2a, nullptr, nullptr, nullptr, nullptr, nullptr, nullptr, nullptr, NN, HIDC, CIN);

  // ---- tower 2 layer 2: U = z1*W1 (bf16 + fused Z prep f32+bf16), then b512 chain (bf16, K=8) ----
  k_gemm<128,64,0,0,0,0,0,1,0,1,0><<<dim3(8, 32), 256, 0, stream>>>(
      z1sbf, w_g2W1t, nullptr, Ubf, nullptr, nullptr, nullptr, nullptr, Zb, Zbh, dc, nullptr, nullptr, NN, HIDC, HIDC);
  k_b512h<0><<<1024, 256, 0, stream>>>(Zbh, Zb, Zbh, XAh, nullptr, nullptr, rpAT, colAT, di, 1.0f, nullptr, nullptr, nullptr, nullptr);
  {
    u16 *curp = XAh, *prv = Zbh;
    for (int k = 2; k < K_CH; ++k){
      u16* nxt = (k == 2) ? XBh : prv;
      k_b512h<0><<<1024, 256, 0, stream>>>(curp, Zb, prv, nxt, nullptr, nullptr, rpAT, colAT, di, omg[k], nullptr, nullptr, nullptr, nullptr);
      prv = curp; curp = nxt;
    }
    k_b512h<1><<<1024, 256, 0, stream>>>(curp, Zb, prv, nullptr, ztmp, z22bf, rpAT, colAT, di, omg[K_CH], dc, Ubf, g2b1, g2a);
  }
  k_segsum<<<NG, 256, 0, stream>>>(z1s, ztmp, gptr, gvbf + 64*1024);

  // ---- MLP1 on stacked zsbf = [z21bf|z22bf], M=8192 (skip branch bf16 in sbh) ----
  k_gemm<128,64,0,0,0,0,0,0,0,0,1><<<dim3(16, 64), 256, 0, stream>>>(
      zsbf, w_m1WsW1t, nullptr, h1, m1bs, nullptr, nullptr, nullptr, nullptr, sbh, nullptr, m1b1, m1a1, 8192, 1024, HIDC);
  k_gemm<128,64,2,0,1,0,0,0,0,1,0><<<dim3(8, 64), 256, 0, stream>>>(
      h1, w_m1W2t, nullptr, h2, m1b2, m1a2, nullptr, nullptr, nullptr, nullptr, nullptr, nullptr, nullptr, 8192, HIDC, HIDC);
  k_gemm<128,64,2,2,1,0,1,0,1,0,0><<<dim3(8, 64), 256, 0, stream>>>(
      h2, w_m1W3t, out, nullptr, m1b3, m1a3, nullptr, out + 2129920, nullptr, sbh, nullptr, nullptr, nullptr, 8192, HIDC, HIDC);

  // ---- MLP2 on stacked gvbf [128,1024], split-K ----
  k_gemm<64,64,0,0,0,128,0,0,1,0,0><<<dim3(16, 2, 8), 256, 0, stream>>>(
      gvbf, w_m2WsW1t, gpart, nullptr, nullptr, nullptr, nullptr, nullptr, nullptr, nullptr, nullptr, nullptr, nullptr, 128, 1024, 1024);
  k_red<0><<<512, 256, 0, stream>>>(gpart, 8, 1024, m2bs, nullptr, m2b1, m2a1, gsb, gh1bf, nullptr, nullptr, nullptr);
  k_gemm<64,64,0,0,0,64,0,0,1,0,0><<<dim3(8, 2, 8), 256, 0, stream>>>(
      gh1bf, w_m2W2t, gpart, nullptr, nullptr, nullptr, nullptr, nullptr, nullptr, nullptr, nullptr, nullptr, nullptr, 128, HIDC, HIDC);
  k_red<1><<<256, 256, 0, stream>>>(gpart, 8, 512, m2b2, m2a2, nullptr, nullptr, nullptr, gh2bf, nullptr, nullptr, nullptr);
  k_gemm<64,64,0,0,0,64,0,0,1,0,0><<<dim3(8, 2, 8), 256, 0, stream>>>(
      gh2bf, w_m2W3t, gpart, nullptr, nullptr, nullptr, nullptr, nullptr, nullptr, nullptr, nullptr, nullptr, nullptr, 128, HIDC, HIDC);
  k_red<2><<<256, 256, 0, stream>>>(gpart, 8, 512, m2b3, m2a3, nullptr, nullptr, nullptr, nullptr, gsb, out + 2097152, out + 4227072);
}